// Round 11
// baseline (403.417 us; speedup 1.0000x reference)
//
#include <hip/hip_runtime.h>

typedef float  f32x4 __attribute__((ext_vector_type(4)));
typedef short  s16x8 __attribute__((ext_vector_type(8)));
typedef unsigned short u16x8 __attribute__((ext_vector_type(8)));

#define NROWS 4096
#define ALPHA_LR 0.2f
#define SCALE 0.0625f
#define SLICE 1024

static __device__ __forceinline__ unsigned short bf16_rne(float x) {
    unsigned u = __float_as_uint(x);
    u += 0x7fffu + ((u >> 16) & 1u);
    return (unsigned short)(u >> 16);
}
static __device__ __forceinline__ unsigned short bf16_trunc(float x) {
    return (unsigned short)(__float_as_uint(x) >> 16);
}
static __device__ __forceinline__ float bf2f(unsigned short h) {
    return __uint_as_float(((unsigned)h) << 16);
}
static __device__ __forceinline__ float wmax16(float v) {
#pragma unroll
    for (int o = 8; o; o >>= 1) v = fmaxf(v, __shfl_xor(v, o, 16));
    return v;
}
static __device__ __forceinline__ float wsum16(float v) {
#pragma unroll
    for (int o = 8; o; o >>= 1) v += __shfl_xor(v, o, 16);
    return v;
}

// ---------------------------------------------------------------------------
// Split fp32 A-side matrices to bf16 hi/lo (grid-stride).
// ---------------------------------------------------------------------------
__global__ __launch_bounds__(256) void wprep(
    const float* __restrict__ W, const float* __restrict__ Wq,
    const float* __restrict__ Wl, const float* __restrict__ hsrc,
    unsigned short* __restrict__ Whi, unsigned short* __restrict__ Wlo,
    unsigned short* __restrict__ Qhi, unsigned short* __restrict__ Qlo,
    unsigned short* __restrict__ WLhi, unsigned short* __restrict__ WLlo,
    unsigned short* __restrict__ Hhi, unsigned short* __restrict__ Hlo)
{
    for (int i = blockIdx.x * 256 + threadIdx.x; i < 2097152; i += gridDim.x * 256) {
        if (i < 131072) {
            float v = W[i];
            unsigned short hh = bf16_trunc(v);
            Whi[i] = hh; Wlo[i] = bf16_rne(v - bf2f(hh));
        }
        if (i < 196608) {
            float v = Wq[i];
            unsigned short hh = bf16_trunc(v);
            Qhi[i] = hh; Qlo[i] = bf16_rne(v - bf2f(hh));
        }
        if (i < 65536) {
            float v = Wl[i];
            unsigned short hh = bf16_trunc(v);
            WLhi[i] = hh; WLlo[i] = bf16_rne(v - bf2f(hh));
        }
        {
            float v = hsrc[i];
            unsigned short hh = bf16_trunc(v);
            Hhi[i] = hh; Hlo[i] = bf16_rne(v - bf2f(hh));
        }
    }
}

// ---------------------------------------------------------------------------
// MFMA GEMM, 3-term bf16 hi/lo split, A pre-split (r10, unchanged).
// ---------------------------------------------------------------------------
template <int EPI, bool BIAS>
__global__ __launch_bounds__(256) void gemm_mfma(
    const unsigned short* __restrict__ Ahi, const unsigned short* __restrict__ Alo,
    const unsigned short* __restrict__ Bhi, const unsigned short* __restrict__ Blo,
    const float* __restrict__ bias,
    unsigned short* __restrict__ o0, unsigned short* __restrict__ o1,
    unsigned short* __restrict__ o2,
    int M, int Nn, int K)
{
    __shared__ unsigned short Ah[64][40];
    __shared__ unsigned short Al[64][40];
    __shared__ unsigned short Bh[64][40];
    __shared__ unsigned short Bl[64][40];

    const int tid = threadIdx.x;
    const int w = tid >> 6;
    const int ln = tid & 63;
    const int l15 = ln & 15;
    const int lhi = ln >> 4;
    const int bm = blockIdx.y * 64;
    const int bn = blockIdx.x * 64;
    const int sm = tid >> 2;
    const int sk = (tid & 3) * 8;

    f32x4 acc[4];
#pragma unroll
    for (int cf = 0; cf < 4; ++cf) acc[cf] = (f32x4){0.f, 0.f, 0.f, 0.f};

    const unsigned short* ahrow = &Ahi[(size_t)(bm + sm) * K];
    const unsigned short* alrow = &Alo[(size_t)(bm + sm) * K];
    const unsigned short* bhrow = &Bhi[(size_t)(bn + sm) * K];
    const unsigned short* blrow = &Blo[(size_t)(bn + sm) * K];

    uint4 ahr = *(const uint4*)(ahrow + sk);
    uint4 alr = *(const uint4*)(alrow + sk);
    uint4 bhr = *(const uint4*)(bhrow + sk);
    uint4 blr = *(const uint4*)(blrow + sk);

    for (int k0 = 0; k0 < K; k0 += 32) {
        __syncthreads();
        *(uint4*)&Ah[sm][sk] = ahr;
        *(uint4*)&Al[sm][sk] = alr;
        *(uint4*)&Bh[sm][sk] = bhr;
        *(uint4*)&Bl[sm][sk] = blr;
        const int kn = (k0 + 32 < K) ? k0 + 32 : 0;
        ahr = *(const uint4*)(ahrow + kn + sk);
        alr = *(const uint4*)(alrow + kn + sk);
        bhr = *(const uint4*)(bhrow + kn + sk);
        blr = *(const uint4*)(blrow + kn + sk);
        __syncthreads();
        s16x8 ah = *(const s16x8*)&Ah[w * 16 + l15][lhi * 8];
        s16x8 al2 = *(const s16x8*)&Al[w * 16 + l15][lhi * 8];
        __builtin_amdgcn_s_setprio(1);
#pragma unroll
        for (int cf = 0; cf < 4; ++cf) {
            s16x8 bh = *(const s16x8*)&Bh[cf * 16 + l15][lhi * 8];
            s16x8 bl = *(const s16x8*)&Bl[cf * 16 + l15][lhi * 8];
            acc[cf] = __builtin_amdgcn_mfma_f32_16x16x32_bf16(ah, bh, acc[cf], 0, 0, 0);
            acc[cf] = __builtin_amdgcn_mfma_f32_16x16x32_bf16(ah, bl, acc[cf], 0, 0, 0);
            acc[cf] = __builtin_amdgcn_mfma_f32_16x16x32_bf16(al2, bh, acc[cf], 0, 0, 0);
        }
        __builtin_amdgcn_s_setprio(0);
    }

#pragma unroll
    for (int cf = 0; cf < 4; ++cf) {
        const int col = bn + cf * 16 + l15;
        float bv = BIAS ? bias[col] : 0.0f;
#pragma unroll
        for (int r = 0; r < 4; ++r) {
            const int row = bm + w * 16 + lhi * 4 + r;
            float v = acc[cf][r] + bv;
            if (EPI == 1) {
                unsigned short hh = bf16_trunc(v);
                o0[(size_t)row * Nn + col] = hh;
                o1[(size_t)row * Nn + col] = bf16_rne(v - bf2f(hh));
                o2[(size_t)col * NROWS + row] = bf16_rne(v);
            } else if (EPI == 2) {
                if (col < 256)      o0[(size_t)row * 256 + col] = bf16_rne(v);
                else if (col < 512) o1[(size_t)row * 256 + (col - 256)] = bf16_rne(v);
                else                o2[(size_t)(col - 512) * NROWS + row] = bf16_rne(v);
            } else {
                unsigned short hh = bf16_trunc(v);
                o0[(size_t)row * Nn + col] = hh;
                o1[(size_t)row * Nn + col] = bf16_rne(v - bf2f(hh));
            }
        }
    }
}

// ---------------------------------------------------------------------------
// p1 = Wh @ a[:256], p2 = Wh @ a[256:]
// ---------------------------------------------------------------------------
__global__ __launch_bounds__(256) void compute_p(
    const unsigned short* __restrict__ WhbHi, const unsigned short* __restrict__ WhbLo,
    const float* __restrict__ a, float* __restrict__ p1, float* __restrict__ p2)
{
    const int row = blockIdx.x * 16 + (threadIdx.x >> 4);
    const int c = threadIdx.x & 15;
    float s1 = 0.f, s2 = 0.f;
    for (int f = c; f < 256; f += 16) {
        size_t idx = (size_t)row * 256 + f;
        float w = bf2f(WhbHi[idx]) + bf2f(WhbLo[idx]);
        s1 += w * a[f];
        s2 += w * a[256 + f];
    }
    s1 = wsum16(s1);
    s2 = wsum16(s2);
    if (c == 0) { p1[row] = s1; p2[row] = s2; }
}

// ---------------------------------------------------------------------------
// Global max of p2 (single block).
// ---------------------------------------------------------------------------
__global__ __launch_bounds__(256) void p2max_kernel(
    const float* __restrict__ p2, float* __restrict__ p2m)
{
    __shared__ float red[4];
    const int tid = threadIdx.x;
    float v = -3.0e38f;
#pragma unroll
    for (int k = 0; k < 16; ++k) v = fmaxf(v, p2[tid + k * 256]);
#pragma unroll
    for (int o = 32; o; o >>= 1) v = fmaxf(v, __shfl_xor(v, o, 64));
    if ((tid & 63) == 0) red[tid >> 6] = v;
    __syncthreads();
    if (tid == 0) p2m[0] = fmaxf(fmaxf(red[0], red[1]), fmaxf(red[2], red[3]));
}

// ---------------------------------------------------------------------------
// norms1/norms2: Cauchy-Schwarz bound M[i][h] = ||q_i||*max||k||/16.
// ---------------------------------------------------------------------------
__global__ __launch_bounds__(256) void norms1(
    const unsigned short* __restrict__ qh, const unsigned short* __restrict__ kh,
    float* __restrict__ qn2, float* __restrict__ knp)
{
    __shared__ float kn[16][4];
    const int tid = threadIdx.x;
    const int r16 = tid >> 4;
    const int c = tid & 15;
    const int i = blockIdx.x * 16 + r16;
#pragma unroll
    for (int h = 0; h < 4; ++h) {
        float sq = 0.f, sk = 0.f;
#pragma unroll
        for (int d = 0; d < 4; ++d) {
            float qv = bf2f(qh[(size_t)i * 256 + h * 64 + c + d * 16]);
            float kv = bf2f(kh[(size_t)i * 256 + h * 64 + c + d * 16]);
            sq += qv * qv; sk += kv * kv;
        }
        sq = wsum16(sq); sk = wsum16(sk);
        if (c == 0) { qn2[i * 4 + h] = sq; kn[r16][h] = sk; }
    }
    __syncthreads();
    if (tid < 4) {
        float m = 0.f;
#pragma unroll
        for (int r = 0; r < 16; ++r) m = fmaxf(m, kn[r][tid]);
        knp[blockIdx.x * 4 + tid] = m;
    }
}

__global__ __launch_bounds__(256) void norms2(
    const float* __restrict__ qn2, const float* __restrict__ knp,
    float* __restrict__ Mb)
{
    __shared__ float red[4][4];
    __shared__ float kmax[4];
    const int tid = threadIdx.x;
    float v[4];
#pragma unroll
    for (int h = 0; h < 4; ++h) v[h] = knp[tid * 4 + h];
#pragma unroll
    for (int h = 0; h < 4; ++h)
#pragma unroll
        for (int o = 32; o; o >>= 1) v[h] = fmaxf(v[h], __shfl_xor(v[h], o, 64));
    if ((tid & 63) == 0) {
#pragma unroll
        for (int h = 0; h < 4; ++h) red[tid >> 6][h] = v[h];
    }
    __syncthreads();
    if (tid < 4)
        kmax[tid] = fmaxf(fmaxf(red[0][tid], red[1][tid]), fmaxf(red[2][tid], red[3][tid]));
    __syncthreads();
    const int i = blockIdx.x * 256 + tid;
#pragma unroll
    for (int h = 0; h < 4; ++h)
        Mb[i * 4 + h] = sqrtf(qn2[i * 4 + h] * kmax[h]) * SCALE;
}

// ---------------------------------------------------------------------------
// Pass A: swapped QK (mfma(K,Q)) + exp -> p~ (bf16, A-frag-TILED layout) + z.
// Tiled layout: [h][itl(64)][jb32(128)] x 1KB; within tile, byte = lane*16
// holds p~[i=lane&15][j = (lane>>4)*8 .. +7]. No LDS, no barriers.
// grid = 16 j-chunks x 64 itl (1024 blocks); wave = head.
// ---------------------------------------------------------------------------
__global__ __launch_bounds__(256) void qkexp_kernel(
    const unsigned short* __restrict__ qh_g, const unsigned short* __restrict__ kh_g,
    const float* __restrict__ Mb, unsigned short* __restrict__ pt_g,
    float* __restrict__ z_g, int sbase)
{
    const int tid = threadIdx.x;
    const int w = tid >> 6;
    const int ln = tid & 63;
    const int l15 = ln & 15;
    const int lhi = ln >> 4;
    const int itl = blockIdx.x & 63;
    const int ch  = blockIdx.x >> 6;     // 0..15
    const int i0 = sbase + itl * 16;
    const int jb0 = ch * 256;            // 8 steps of 32 j

    s16x8 qB[2];
#pragma unroll
    for (int ks = 0; ks < 2; ++ks)
        qB[ks] = *(const s16x8*)(qh_g + (size_t)(i0 + l15) * 256 + w * 64 + ks * 32 + lhi * 8);
    const float Mv = Mb[(i0 + l15) * 4 + w];

    const unsigned short* kBase = kh_g + (size_t)l15 * 256 + w * 64 + lhi * 8;
    // store base: value (i=l15, j_local) -> la = l15 + (t*2 + (lhi>>1))*16, half = lhi&1
    char* tileB = (char*)pt_g + (size_t)(w * 64 + itl) * 128 * 1024
                + (l15 + (lhi >> 1) * 16) * 16 + (lhi & 1) * 8;

    float zacc = 0.f;
    s16x8 kA[2][2];
#pragma unroll
    for (int t = 0; t < 2; ++t)
#pragma unroll
        for (int ks = 0; ks < 2; ++ks)
            kA[t][ks] = *(const s16x8*)(kBase + (size_t)(jb0 + t * 16) * 256 + ks * 32);

    for (int tt = 0; tt < 8; ++tt) {
        const int j0 = jb0 + tt * 32;
        const int jn = jb0 + ((tt + 1) & 7) * 32;
        f32x4 acc[2] = {{0.f,0.f,0.f,0.f},{0.f,0.f,0.f,0.f}};
        __builtin_amdgcn_s_setprio(1);
#pragma unroll
        for (int t = 0; t < 2; ++t) {
            acc[t] = __builtin_amdgcn_mfma_f32_16x16x32_bf16(kA[t][0], qB[0], acc[t], 0, 0, 0);
            acc[t] = __builtin_amdgcn_mfma_f32_16x16x32_bf16(kA[t][1], qB[1], acc[t], 0, 0, 0);
        }
        __builtin_amdgcn_s_setprio(0);
        // prefetch next step's K
#pragma unroll
        for (int t = 0; t < 2; ++t)
#pragma unroll
            for (int ks = 0; ks < 2; ++ks)
                kA[t][ks] = *(const s16x8*)(kBase + (size_t)(jn + t * 16) * 256 + ks * 32);
        // exp + pack + store (8B per t), z accumulate
#pragma unroll
        for (int t = 0; t < 2; ++t) {
            float e0 = __expf(fmaf(acc[t][0], SCALE, -Mv));
            float e1 = __expf(fmaf(acc[t][1], SCALE, -Mv));
            float e2 = __expf(fmaf(acc[t][2], SCALE, -Mv));
            float e3 = __expf(fmaf(acc[t][3], SCALE, -Mv));
            zacc += (e0 + e1) + (e2 + e3);
            ushort4 pk;
            pk.x = bf16_rne(e0); pk.y = bf16_rne(e1);
            pk.z = bf16_rne(e2); pk.w = bf16_rne(e3);
            *(ushort4*)(tileB + (size_t)(j0 >> 5) * 1024 + t * 512) = pk;
        }
    }
    zacc += __shfl_xor(zacc, 16);
    zacc += __shfl_xor(zacc, 32);
    if (ln < 16) atomicAdd(&z_g[(i0 + ln) * 4 + w], zacc);
}

// ---------------------------------------------------------------------------
// Pass C: per-head PV streaming GEMM. pacc += p~ @ V (raw; iz applied at
// merge). No LDS, no barriers. grid = 16 jch x 64 itl; wave = head.
// ---------------------------------------------------------------------------
__global__ __launch_bounds__(256) void pv_kernel(
    const unsigned short* __restrict__ pt_g, const unsigned short* __restrict__ vth_g,
    float* __restrict__ pacc_g, int sbase)
{
    const int tid = threadIdx.x;
    const int w = tid >> 6;
    const int ln = tid & 63;
    const int l15 = ln & 15;
    const int lhi = ln >> 4;
    const int itl = blockIdx.x & 63;
    const int ch  = blockIdx.x >> 6;
    const int i0 = sbase + itl * 16;
    const int jb0 = ch * 8;              // tile units (8 tiles of 32 j)

    const char* tA = (const char*)pt_g + (size_t)(w * 64 + itl) * 128 * 1024 + ln * 16;
    const unsigned short* vB = vth_g + (size_t)(w * 64 + l15) * 4096 + lhi * 8;

    f32x4 pacc[4];
#pragma unroll
    for (int nt2 = 0; nt2 < 4; ++nt2) pacc[nt2] = (f32x4){0.f, 0.f, 0.f, 0.f};

    s16x8 pA = *(const s16x8*)(tA + (size_t)jb0 * 1024);
    s16x8 vf[4];
#pragma unroll
    for (int nt2 = 0; nt2 < 4; ++nt2)
        vf[nt2] = *(const s16x8*)(vB + (size_t)(nt2 * 16) * 4096 + jb0 * 32);

    for (int tt = 0; tt < 8; ++tt) {
        const int jbn = jb0 + ((tt + 1) & 7);
        __builtin_amdgcn_s_setprio(1);
#pragma unroll
        for (int nt2 = 0; nt2 < 4; ++nt2)
            pacc[nt2] = __builtin_amdgcn_mfma_f32_16x16x32_bf16(pA, vf[nt2], pacc[nt2], 0, 0, 0);
        __builtin_amdgcn_s_setprio(0);
        pA = *(const s16x8*)(tA + (size_t)jbn * 1024);
#pragma unroll
        for (int nt2 = 0; nt2 < 4; ++nt2)
            vf[nt2] = *(const s16x8*)(vB + (size_t)(nt2 * 16) * 4096 + jbn * 32);
    }

#pragma unroll
    for (int nt2 = 0; nt2 < 4; ++nt2)
#pragma unroll
        for (int r = 0; r < 4; ++r)
            atomicAdd(&pacc_g[(size_t)(i0 + lhi * 4 + r) * 256 + w * 64 + nt2 * 16 + l15],
                      pacc[nt2][r]);
}

// ---------------------------------------------------------------------------
// Pass D: elementwise ptil. Reads 4 p~ frags (tiled), dsum in-register,
// mask/lrelu/exp -> ptil (tiled) + row-sum L atomics. No LDS, no barriers.
// grid = 8 jch x 64 itl (512); wave handles 4 j-tiles.
// ---------------------------------------------------------------------------
__global__ __launch_bounds__(256) void ptil_kernel(
    const unsigned short* __restrict__ pt_g, const int* __restrict__ adj,
    const float* __restrict__ p1g, const float* __restrict__ p2g,
    const float* __restrict__ p2m, const float* __restrict__ z_g,
    unsigned short* __restrict__ ptil_g, float* __restrict__ Lp_g, int sbase)
{
    const int tid = threadIdx.x;
    const int w = tid >> 6;
    const int ln = tid & 63;
    const int l15 = ln & 15;
    const int lhi = ln >> 4;
    const int itl = blockIdx.x & 63;
    const int ch  = blockIdx.x >> 6;     // 0..7
    const int i = sbase + itl * 16 + l15;

    const float p1v = p1g[i];
    float Mfix;
    {
        float s = p1v + p2m[0];
        Mfix = (s > 0.f ? s : ALPHA_LR * s) + 4.0f;
    }
    float izv[4];
#pragma unroll
    for (int h = 0; h < 4; ++h) izv[h] = 1.0f / z_g[i * 4 + h];

    float Lacc = 0.f;
#pragma unroll
    for (int t = 0; t < 4; ++t) {
        const int jb = ch * 16 + w * 4 + t;       // 0..127
        const int j8 = jb * 32 + lhi * 8;
        u16x8 f0 = *(const u16x8*)((const char*)pt_g + (size_t)(0 * 64 + itl) * 128 * 1024 + (size_t)jb * 1024 + ln * 16);
        u16x8 f1 = *(const u16x8*)((const char*)pt_g + (size_t)(1 * 64 + itl) * 128 * 1024 + (size_t)jb * 1024 + ln * 16);
        u16x8 f2 = *(const u16x8*)((const char*)pt_g + (size_t)(2 * 64 + itl) * 128 * 1024 + (size_t)jb * 1024 + ln * 16);
        u16x8 f3 = *(const u16x8*)((const char*)pt_g + (size_t)(3 * 64 + itl) * 128 * 1024 + (size_t)jb * 1024 + ln * 16);
        int4 a0 = *(const int4*)(adj + (size_t)i * 4096 + j8);
        int4 a1 = *(const int4*)(adj + (size_t)i * 4096 + j8 + 4);
        float4 q0 = *(const float4*)(p2g + j8);
        float4 q1 = *(const float4*)(p2g + j8 + 4);
        int am[8] = {a0.x, a0.y, a0.z, a0.w, a1.x, a1.y, a1.z, a1.w};
        float pv[8] = {q0.x, q0.y, q0.z, q0.w, q1.x, q1.y, q1.z, q1.w};
        u16x8 outp;
#pragma unroll
        for (int e = 0; e < 8; ++e) {
            float ds = bf2f((unsigned short)f0[e]) * izv[0]
                     + bf2f((unsigned short)f1[e]) * izv[1]
                     + bf2f((unsigned short)f2[e]) * izv[2]
                     + bf2f((unsigned short)f3[e]) * izv[3];
            float ee = p1v + pv[e];
            ee = ee > 0.f ? ee : ALPHA_LR * ee;
            float pr = (am[e] > 0) ? __expf(ee + ds - Mfix) : 0.f;
            Lacc += pr;
            outp[e] = bf16_rne(pr);
        }
        *(u16x8*)((char*)ptil_g + (size_t)itl * 128 * 1024 + (size_t)jb * 1024 + ln * 16) = outp;
    }
    Lacc += __shfl_xor(Lacc, 16);
    Lacc += __shfl_xor(Lacc, 32);
    if (ln < 16) atomicAdd(&Lp_g[sbase + itl * 16 + ln], Lacc);
}

// ---------------------------------------------------------------------------
// Pass E: wacc += ptil @ Wh. Streaming GEMM like pass C; wave = col-quarter.
// ---------------------------------------------------------------------------
__global__ __launch_bounds__(256) void awh_kernel(
    const unsigned short* __restrict__ ptil_g, const unsigned short* __restrict__ wht_g,
    float* __restrict__ wacc_g, int sbase)
{
    const int tid = threadIdx.x;
    const int w = tid >> 6;
    const int ln = tid & 63;
    const int l15 = ln & 15;
    const int lhi = ln >> 4;
    const int itl = blockIdx.x & 63;
    const int ch  = blockIdx.x >> 6;
    const int i0 = sbase + itl * 16;
    const int jb0 = ch * 8;

    const char* tA = (const char*)ptil_g + (size_t)itl * 128 * 1024 + ln * 16;
    const unsigned short* wB = wht_g + (size_t)(w * 64 + l15) * 4096 + lhi * 8;

    f32x4 acc[4];
#pragma unroll
    for (int nt = 0; nt < 4; ++nt) acc[nt] = (f32x4){0.f, 0.f, 0.f, 0.f};

    s16x8 pA = *(const s16x8*)(tA + (size_t)jb0 * 1024);
    s16x8 wf[4];
#pragma unroll
    for (int nt = 0; nt < 4; ++nt)
        wf[nt] = *(const s16x8*)(wB + (size_t)(nt * 16) * 4096 + jb0 * 32);

    for (int tt = 0; tt < 8; ++tt) {
        const int jbn = jb0 + ((tt + 1) & 7);
        __builtin_amdgcn_s_setprio(1);
#pragma unroll
        for (int nt = 0; nt < 4; ++nt)
            acc[nt] = __builtin_amdgcn_mfma_f32_16x16x32_bf16(pA, wf[nt], acc[nt], 0, 0, 0);
        __builtin_amdgcn_s_setprio(0);
        pA = *(const s16x8*)(tA + (size_t)jbn * 1024);
#pragma unroll
        for (int nt = 0; nt < 4; ++nt)
            wf[nt] = *(const s16x8*)(wB + (size_t)(nt * 16) * 4096 + jbn * 32);
    }

#pragma unroll
    for (int nt = 0; nt < 4; ++nt)
#pragma unroll
        for (int r = 0; r < 4; ++r)
            atomicAdd(&wacc_g[(size_t)(i0 + lhi * 4 + r) * 256 + w * 64 + nt * 16 + l15],
                      acc[nt][r]);
}

// ---------------------------------------------------------------------------
// Merge: Wh0 = pacc*iz -> row softmax; out = elu(wacc*invL + softmax(Wh0)).
// ---------------------------------------------------------------------------
__global__ __launch_bounds__(256) void merge_kernel(
    const float* __restrict__ pacc_g, const float* __restrict__ wacc_g,
    const float* __restrict__ z_g, const float* __restrict__ Lp,
    float* __restrict__ out)
{
    const int rt = blockIdx.x;
    const int tid = threadIdx.x;
    const int row = tid >> 4;
    const int cg = tid & 15;
    const int i = rt * 16 + row;

    const float iz = 1.0f / z_g[i * 4 + (cg >> 2)];   // head = cg>>2 (16-col group within one head)
    const float invL = 1.0f / fmaxf(Lp[i], 1e-30f);

    float p[16], wv[16];
    const size_t b = (size_t)i * 256 + cg * 16;
#pragma unroll
    for (int k4 = 0; k4 < 4; ++k4) {
        float4 pvv = *(const float4*)(pacc_g + b + k4 * 4);
        float4 wvv = *(const float4*)(wacc_g + b + k4 * 4);
        p[k4*4+0] = pvv.x * iz; p[k4*4+1] = pvv.y * iz; p[k4*4+2] = pvv.z * iz; p[k4*4+3] = pvv.w * iz;
        wv[k4*4+0] = wvv.x; wv[k4*4+1] = wvv.y; wv[k4*4+2] = wvv.z; wv[k4*4+3] = wvv.w;
    }

    float mx = -3.0e38f;
#pragma unroll
    for (int k = 0; k < 16; ++k) mx = fmaxf(mx, p[k]);
    mx = wmax16(mx);
    float sm = 0.f;
#pragma unroll
    for (int k = 0; k < 16; ++k) { p[k] = __expf(p[k] - mx); sm += p[k]; }
    sm = wsum16(sm);
    const float inv = 1.0f / sm;

    float* orow = out + (size_t)i * 256 + cg * 16;
#pragma unroll
    for (int k4 = 0; k4 < 4; ++k4) {
        float4 o;
        float v;
        v = wv[k4*4+0] * invL + p[k4*4+0] * inv; o.x = v > 0.f ? v : __expf(v) - 1.f;
        v = wv[k4*4+1] * invL + p[k4*4+1] * inv; o.y = v > 0.f ? v : __expf(v) - 1.f;
        v = wv[k4*4+2] * invL + p[k4*4+2] * inv; o.z = v > 0.f ? v : __expf(v) - 1.f;
        v = wv[k4*4+3] * invL + p[k4*4+3] * inv; o.w = v > 0.f ? v : __expf(v) - 1.f;
        *(float4*)(orow + k4 * 4) = o;
    }
}

extern "C" void kernel_launch(void* const* d_in, const int* in_sizes, int n_in,
                              void* d_out, int out_size, void* d_ws, size_t ws_size,
                              hipStream_t stream)
{
    const float* h      = (const float*)d_in[0];
    const int*   adj    = (const int*)d_in[1];
    const float* W      = (const float*)d_in[2];
    const float* Wl_w   = (const float*)d_in[3];
    const float* Wl_b   = (const float*)d_in[4];
    const float* Wqkv_w = (const float*)d_in[5];
    const float* Wqkv_b = (const float*)d_in[6];
    const float* a      = (const float*)d_in[7];
    float* out = (float*)d_out;

    char* wsb = (char*)d_ws;
    unsigned short* qh     = (unsigned short*)(wsb + 0);          // 2 MB
    unsigned short* kh     = (unsigned short*)(wsb + 2097152);    // 2 MB
    unsigned short* vth    = (unsigned short*)(wsb + 4194304);    // 2 MB  (vT [256][4096])
    unsigned short* wht    = (unsigned short*)(wsb + 6291456);    // 2 MB  (WhT [256][4096])
    float*          pacc_f = (float*)(wsb + 8388608);             // 4 MB
    float*          wacc_f = (float*)(wsb + 12582912);            // 4 MB
    unsigned short* pt     = (unsigned short*)(wsb + 16777216);   // 32 MB (p~ slice, tiled)
    unsigned short* ptilb  = (unsigned short*)(wsb + 50331648);   // 8 MB  (ptil slice, tiled)
    float*          p1b    = (float*)(wsb + 58720256);
    float*          p2b    = (float*)(wsb + 58736640);
    float*          p2m    = (float*)(wsb + 58753024);
    float*          qn2    = (float*)(wsb + 58769408);            // 64 KB
    float*          knp    = (float*)(wsb + 58834944);            // 16 KB
    float*          Mb     = (float*)(wsb + 58851328);            // 64 KB
    float*          z_g    = (float*)(wsb + 58916864);            // 64 KB
    float*          Lp     = (float*)(wsb + 58982400);            // 16 KB
    // gemm-phase temporaries overlay the p~ region (dead before pass A)
    unsigned short* Hhi    = (unsigned short*)(wsb + 16777216);   // 4 MB
    unsigned short* Hlo    = (unsigned short*)(wsb + 20971520);   // 4 MB
    unsigned short* WhbHi  = (unsigned short*)(wsb + 25165824);   // 2 MB
    unsigned short* WhbLo  = (unsigned short*)(wsb + 27262976);   // 2 MB
    unsigned short* Whi    = (unsigned short*)(wsb + 29360128);   // 256 KB
    unsigned short* Wlo    = (unsigned short*)(wsb + 29622272);
    unsigned short* Qhi    = (unsigned short*)(wsb + 29884416);   // 384 KB
    unsigned short* Qlo    = (unsigned short*)(wsb + 30277632);
    unsigned short* WLhi   = (unsigned short*)(wsb + 30670848);   // 128 KB
    unsigned short* WLlo   = (unsigned short*)(wsb + 30801920);
    unsigned short* WcThi  = (unsigned short*)(wsb + 30932992);   // 256 KB
    unsigned short* WcTlo  = (unsigned short*)(wsb + 31195136);

    hipMemsetAsync(pacc_f, 0, 4194304, stream);
    hipMemsetAsync(wacc_f, 0, 4194304, stream);
    hipMemsetAsync(z_g, 0, 65536, stream);
    hipMemsetAsync(Lp, 0, 16384, stream);

    dim3 blk(256);
    wprep<<<dim3(2048), blk, 0, stream>>>(W, Wqkv_w, Wl_w, h,
        Whi, Wlo, Qhi, Qlo, WLhi, WLlo, Hhi, Hlo);
    gemm_mfma<3, false><<<dim3(8, 4), blk, 0, stream>>>(
        WLhi, WLlo, Whi, Wlo, nullptr, WcThi, WcTlo, nullptr, 256, 512, 256);
    gemm_mfma<1, true><<<dim3(4, 64), blk, 0, stream>>>(
        Hhi, Hlo, WcThi, WcTlo, Wl_b, WhbHi, WhbLo, wht, 4096, 256, 512);
    gemm_mfma<2, true><<<dim3(12, 64), blk, 0, stream>>>(
        WhbHi, WhbLo, Qhi, Qlo, Wqkv_b, qh, kh, vth, 4096, 768, 256);
    compute_p<<<dim3(256), blk, 0, stream>>>(WhbHi, WhbLo, a, p1b, p2b);
    p2max_kernel<<<dim3(1), blk, 0, stream>>>(p2b, p2m);
    norms1<<<dim3(256), blk, 0, stream>>>(qh, kh, qn2, knp);
    norms2<<<dim3(16), blk, 0, stream>>>(qn2, knp, Mb);

    for (int s = 0; s < 4; ++s) {
        const int sbase = s * SLICE;
        qkexp_kernel<<<dim3(1024), blk, 0, stream>>>(qh, kh, Mb, pt, z_g, sbase);
        pv_kernel<<<dim3(1024), blk, 0, stream>>>(pt, vth, pacc_f, sbase);
        ptil_kernel<<<dim3(512), blk, 0, stream>>>(pt, adj, p1b, p2b, p2m, z_g, ptilb, Lp, sbase);
        awh_kernel<<<dim3(1024), blk, 0, stream>>>(ptilb, wht, wacc_f, sbase);
    }
    merge_kernel<<<dim3(256), blk, 0, stream>>>(pacc_f, wacc_f, z_g, Lp, out);
}

// Round 12
// 328.352 us; speedup vs baseline: 1.2286x; 1.2286x over previous
//
#include <hip/hip_runtime.h>

typedef float  f32x4 __attribute__((ext_vector_type(4)));
typedef short  s16x8 __attribute__((ext_vector_type(8)));
typedef unsigned short u16x8 __attribute__((ext_vector_type(8)));

#define NROWS 4096
#define ALPHA_LR 0.2f
#define SCALE 0.0625f
#define PT_HSTRIDE 33554432ull   // 32 MB per head: [256 itl][128 jb] x 1KB

static __device__ __forceinline__ unsigned short bf16_rne(float x) {
    unsigned u = __float_as_uint(x);
    u += 0x7fffu + ((u >> 16) & 1u);
    return (unsigned short)(u >> 16);
}
static __device__ __forceinline__ unsigned short bf16_trunc(float x) {
    return (unsigned short)(__float_as_uint(x) >> 16);
}
static __device__ __forceinline__ float bf2f(unsigned short h) {
    return __uint_as_float(((unsigned)h) << 16);
}
static __device__ __forceinline__ float wmax16(float v) {
#pragma unroll
    for (int o = 8; o; o >>= 1) v = fmaxf(v, __shfl_xor(v, o, 16));
    return v;
}
static __device__ __forceinline__ float wsum16(float v) {
#pragma unroll
    for (int o = 8; o; o >>= 1) v += __shfl_xor(v, o, 16);
    return v;
}

// ---------------------------------------------------------------------------
// Split fp32 A-side matrices to bf16 hi/lo (grid-stride).
// ---------------------------------------------------------------------------
__global__ __launch_bounds__(256) void wprep(
    const float* __restrict__ W, const float* __restrict__ Wq,
    const float* __restrict__ Wl, const float* __restrict__ hsrc,
    unsigned short* __restrict__ Whi, unsigned short* __restrict__ Wlo,
    unsigned short* __restrict__ Qhi, unsigned short* __restrict__ Qlo,
    unsigned short* __restrict__ WLhi, unsigned short* __restrict__ WLlo,
    unsigned short* __restrict__ Hhi, unsigned short* __restrict__ Hlo)
{
    for (int i = blockIdx.x * 256 + threadIdx.x; i < 2097152; i += gridDim.x * 256) {
        if (i < 131072) {
            float v = W[i];
            unsigned short hh = bf16_trunc(v);
            Whi[i] = hh; Wlo[i] = bf16_rne(v - bf2f(hh));
        }
        if (i < 196608) {
            float v = Wq[i];
            unsigned short hh = bf16_trunc(v);
            Qhi[i] = hh; Qlo[i] = bf16_rne(v - bf2f(hh));
        }
        if (i < 65536) {
            float v = Wl[i];
            unsigned short hh = bf16_trunc(v);
            WLhi[i] = hh; WLlo[i] = bf16_rne(v - bf2f(hh));
        }
        {
            float v = hsrc[i];
            unsigned short hh = bf16_trunc(v);
            Hhi[i] = hh; Hlo[i] = bf16_rne(v - bf2f(hh));
        }
    }
}

// ---------------------------------------------------------------------------
// MFMA GEMM, 3-term bf16 hi/lo split, A pre-split (unchanged).
// ---------------------------------------------------------------------------
template <int EPI, bool BIAS>
__global__ __launch_bounds__(256) void gemm_mfma(
    const unsigned short* __restrict__ Ahi, const unsigned short* __restrict__ Alo,
    const unsigned short* __restrict__ Bhi, const unsigned short* __restrict__ Blo,
    const float* __restrict__ bias,
    unsigned short* __restrict__ o0, unsigned short* __restrict__ o1,
    unsigned short* __restrict__ o2,
    int M, int Nn, int K)
{
    __shared__ unsigned short Ah[64][40];
    __shared__ unsigned short Al[64][40];
    __shared__ unsigned short Bh[64][40];
    __shared__ unsigned short Bl[64][40];

    const int tid = threadIdx.x;
    const int w = tid >> 6;
    const int ln = tid & 63;
    const int l15 = ln & 15;
    const int lhi = ln >> 4;
    const int bm = blockIdx.y * 64;
    const int bn = blockIdx.x * 64;
    const int sm = tid >> 2;
    const int sk = (tid & 3) * 8;

    f32x4 acc[4];
#pragma unroll
    for (int cf = 0; cf < 4; ++cf) acc[cf] = (f32x4){0.f, 0.f, 0.f, 0.f};

    const unsigned short* ahrow = &Ahi[(size_t)(bm + sm) * K];
    const unsigned short* alrow = &Alo[(size_t)(bm + sm) * K];
    const unsigned short* bhrow = &Bhi[(size_t)(bn + sm) * K];
    const unsigned short* blrow = &Blo[(size_t)(bn + sm) * K];

    uint4 ahr = *(const uint4*)(ahrow + sk);
    uint4 alr = *(const uint4*)(alrow + sk);
    uint4 bhr = *(const uint4*)(bhrow + sk);
    uint4 blr = *(const uint4*)(blrow + sk);

    for (int k0 = 0; k0 < K; k0 += 32) {
        __syncthreads();
        *(uint4*)&Ah[sm][sk] = ahr;
        *(uint4*)&Al[sm][sk] = alr;
        *(uint4*)&Bh[sm][sk] = bhr;
        *(uint4*)&Bl[sm][sk] = blr;
        const int kn = (k0 + 32 < K) ? k0 + 32 : 0;
        ahr = *(const uint4*)(ahrow + kn + sk);
        alr = *(const uint4*)(alrow + kn + sk);
        bhr = *(const uint4*)(bhrow + kn + sk);
        blr = *(const uint4*)(blrow + kn + sk);
        __syncthreads();
        s16x8 ah = *(const s16x8*)&Ah[w * 16 + l15][lhi * 8];
        s16x8 al2 = *(const s16x8*)&Al[w * 16 + l15][lhi * 8];
        __builtin_amdgcn_s_setprio(1);
#pragma unroll
        for (int cf = 0; cf < 4; ++cf) {
            s16x8 bh = *(const s16x8*)&Bh[cf * 16 + l15][lhi * 8];
            s16x8 bl = *(const s16x8*)&Bl[cf * 16 + l15][lhi * 8];
            acc[cf] = __builtin_amdgcn_mfma_f32_16x16x32_bf16(ah, bh, acc[cf], 0, 0, 0);
            acc[cf] = __builtin_amdgcn_mfma_f32_16x16x32_bf16(ah, bl, acc[cf], 0, 0, 0);
            acc[cf] = __builtin_amdgcn_mfma_f32_16x16x32_bf16(al2, bh, acc[cf], 0, 0, 0);
        }
        __builtin_amdgcn_s_setprio(0);
    }

#pragma unroll
    for (int cf = 0; cf < 4; ++cf) {
        const int col = bn + cf * 16 + l15;
        float bv = BIAS ? bias[col] : 0.0f;
#pragma unroll
        for (int r = 0; r < 4; ++r) {
            const int row = bm + w * 16 + lhi * 4 + r;
            float v = acc[cf][r] + bv;
            if (EPI == 1) {
                unsigned short hh = bf16_trunc(v);
                o0[(size_t)row * Nn + col] = hh;
                o1[(size_t)row * Nn + col] = bf16_rne(v - bf2f(hh));
                o2[(size_t)col * NROWS + row] = bf16_rne(v);
            } else if (EPI == 2) {
                if (col < 256)      o0[(size_t)row * 256 + col] = bf16_rne(v);
                else if (col < 512) o1[(size_t)row * 256 + (col - 256)] = bf16_rne(v);
                else                o2[(size_t)(col - 512) * NROWS + row] = bf16_rne(v);
            } else {
                unsigned short hh = bf16_trunc(v);
                o0[(size_t)row * Nn + col] = hh;
                o1[(size_t)row * Nn + col] = bf16_rne(v - bf2f(hh));
            }
        }
    }
}

// ---------------------------------------------------------------------------
// p1 = Wh @ a[:256], p2 = Wh @ a[256:]
// ---------------------------------------------------------------------------
__global__ __launch_bounds__(256) void compute_p(
    const unsigned short* __restrict__ WhbHi, const unsigned short* __restrict__ WhbLo,
    const float* __restrict__ a, float* __restrict__ p1, float* __restrict__ p2)
{
    const int row = blockIdx.x * 16 + (threadIdx.x >> 4);
    const int c = threadIdx.x & 15;
    float s1 = 0.f, s2 = 0.f;
    for (int f = c; f < 256; f += 16) {
        size_t idx = (size_t)row * 256 + f;
        float w = bf2f(WhbHi[idx]) + bf2f(WhbLo[idx]);
        s1 += w * a[f];
        s2 += w * a[256 + f];
    }
    s1 = wsum16(s1);
    s2 = wsum16(s2);
    if (c == 0) { p1[row] = s1; p2[row] = s2; }
}

// ---------------------------------------------------------------------------
// Global max of p2 (single block).
// ---------------------------------------------------------------------------
__global__ __launch_bounds__(256) void p2max_kernel(
    const float* __restrict__ p2, float* __restrict__ p2m)
{
    __shared__ float red[4];
    const int tid = threadIdx.x;
    float v = -3.0e38f;
#pragma unroll
    for (int k = 0; k < 16; ++k) v = fmaxf(v, p2[tid + k * 256]);
#pragma unroll
    for (int o = 32; o; o >>= 1) v = fmaxf(v, __shfl_xor(v, o, 64));
    if ((tid & 63) == 0) red[tid >> 6] = v;
    __syncthreads();
    if (tid == 0) p2m[0] = fmaxf(fmaxf(red[0], red[1]), fmaxf(red[2], red[3]));
}

// ---------------------------------------------------------------------------
// norms1/norms2: Cauchy-Schwarz bound M[i][h] = ||q_i||*max||k||/16.
// ---------------------------------------------------------------------------
__global__ __launch_bounds__(256) void norms1(
    const unsigned short* __restrict__ qh, const unsigned short* __restrict__ kh,
    float* __restrict__ qn2, float* __restrict__ knp)
{
    __shared__ float kn[16][4];
    const int tid = threadIdx.x;
    const int r16 = tid >> 4;
    const int c = tid & 15;
    const int i = blockIdx.x * 16 + r16;
#pragma unroll
    for (int h = 0; h < 4; ++h) {
        float sq = 0.f, sk = 0.f;
#pragma unroll
        for (int d = 0; d < 4; ++d) {
            float qv = bf2f(qh[(size_t)i * 256 + h * 64 + c + d * 16]);
            float kv = bf2f(kh[(size_t)i * 256 + h * 64 + c + d * 16]);
            sq += qv * qv; sk += kv * kv;
        }
        sq = wsum16(sq); sk = wsum16(sk);
        if (c == 0) { qn2[i * 4 + h] = sq; kn[r16][h] = sk; }
    }
    __syncthreads();
    if (tid < 4) {
        float m = 0.f;
#pragma unroll
        for (int r = 0; r < 16; ++r) m = fmaxf(m, kn[r][tid]);
        knp[blockIdx.x * 4 + tid] = m;
    }
}

__global__ __launch_bounds__(256) void norms2(
    const float* __restrict__ qn2, const float* __restrict__ knp,
    float* __restrict__ Mb)
{
    __shared__ float red[4][4];
    __shared__ float kmax[4];
    const int tid = threadIdx.x;
    float v[4];
#pragma unroll
    for (int h = 0; h < 4; ++h) v[h] = knp[tid * 4 + h];
#pragma unroll
    for (int h = 0; h < 4; ++h)
#pragma unroll
        for (int o = 32; o; o >>= 1) v[h] = fmaxf(v[h], __shfl_xor(v[h], o, 64));
    if ((tid & 63) == 0) {
#pragma unroll
        for (int h = 0; h < 4; ++h) red[tid >> 6][h] = v[h];
    }
    __syncthreads();
    if (tid < 4)
        kmax[tid] = fmaxf(fmaxf(red[0][tid], red[1][tid]), fmaxf(red[2][tid], red[3][tid]));
    __syncthreads();
    const int i = blockIdx.x * 256 + tid;
#pragma unroll
    for (int h = 0; h < 4; ++h)
        Mb[i * 4 + h] = sqrtf(qn2[i * 4 + h] * kmax[h]) * SCALE;
}

// ---------------------------------------------------------------------------
// qkexpv: swapped QK -> exp -> p~ (tiled store, full N) + z atomics, then
// in-register shfl permutation to the PV A-fragment and PV accumulate.
// No LDS, no barriers. grid = 16 jch x 256 itl = 4096; wave = head.
// ---------------------------------------------------------------------------
__global__ __launch_bounds__(256) void qkexpv_kernel(
    const unsigned short* __restrict__ qh_g, const unsigned short* __restrict__ kh_g,
    const unsigned short* __restrict__ vth_g, const float* __restrict__ Mb,
    unsigned short* __restrict__ pt_g, float* __restrict__ z_g,
    float* __restrict__ pacc_g)
{
    const int tid = threadIdx.x;
    const int w = tid >> 6;
    const int ln = tid & 63;
    const int l15 = ln & 15;
    const int lhi = ln >> 4;
    const int itl = blockIdx.x & 255;
    const int ch  = blockIdx.x >> 8;     // 0..15
    const int i0 = itl * 16;
    const int jb0 = ch * 256;            // 8 steps of 32 j

    s16x8 qB[2];
#pragma unroll
    for (int ks = 0; ks < 2; ++ks)
        qB[ks] = *(const s16x8*)(qh_g + (size_t)(i0 + l15) * 256 + w * 64 + ks * 32 + lhi * 8);
    const float Mv = Mb[(i0 + l15) * 4 + w];

    const unsigned short* kBase = kh_g + (size_t)l15 * 256 + w * 64 + lhi * 8;
    const unsigned short* vB = vth_g + (size_t)(w * 64 + l15) * 4096 + lhi * 8;

    char* tileB = (char*)pt_g + (size_t)w * PT_HSTRIDE + (size_t)itl * 131072
                + (l15 + (lhi >> 1) * 16) * 16 + (lhi & 1) * 8;

    const int srcA = l15 + ((lhi & 1) * 32);   // lane 16*((lhi&1)*2)
    const int srcB = srcA + 16;
    const int selT = lhi >> 1;

    float zacc = 0.f;
    f32x4 pacc[4];
#pragma unroll
    for (int nt2 = 0; nt2 < 4; ++nt2) pacc[nt2] = (f32x4){0.f, 0.f, 0.f, 0.f};

    s16x8 kA[2][2];
#pragma unroll
    for (int t = 0; t < 2; ++t)
#pragma unroll
        for (int ks = 0; ks < 2; ++ks)
            kA[t][ks] = *(const s16x8*)(kBase + (size_t)(jb0 + t * 16) * 256 + ks * 32);
    s16x8 vf[4];
#pragma unroll
    for (int nt2 = 0; nt2 < 4; ++nt2)
        vf[nt2] = *(const s16x8*)(vB + (size_t)(nt2 * 16) * 4096 + jb0);

    for (int tt = 0; tt < 8; ++tt) {
        const int j0 = jb0 + tt * 32;
        const int jn = jb0 + ((tt + 1) & 7) * 32;

        // ---- QK (swapped: mfma(K, Q) -> S^T) ----
        f32x4 acc[2] = {{0.f,0.f,0.f,0.f},{0.f,0.f,0.f,0.f}};
        __builtin_amdgcn_s_setprio(1);
#pragma unroll
        for (int t = 0; t < 2; ++t) {
            acc[t] = __builtin_amdgcn_mfma_f32_16x16x32_bf16(kA[t][0], qB[0], acc[t], 0, 0, 0);
            acc[t] = __builtin_amdgcn_mfma_f32_16x16x32_bf16(kA[t][1], qB[1], acc[t], 0, 0, 0);
        }
        __builtin_amdgcn_s_setprio(0);
        // prefetch K(next)
#pragma unroll
        for (int t = 0; t < 2; ++t)
#pragma unroll
            for (int ks = 0; ks < 2; ++ks)
                kA[t][ks] = *(const s16x8*)(kBase + (size_t)(jn + t * 16) * 256 + ks * 32);

        // ---- exp + pack + p~ store + z ----
        unsigned pk[2][2];
#pragma unroll
        for (int t = 0; t < 2; ++t) {
            float e0 = __expf(fmaf(acc[t][0], SCALE, -Mv));
            float e1 = __expf(fmaf(acc[t][1], SCALE, -Mv));
            float e2 = __expf(fmaf(acc[t][2], SCALE, -Mv));
            float e3 = __expf(fmaf(acc[t][3], SCALE, -Mv));
            zacc += (e0 + e1) + (e2 + e3);
            pk[t][0] = (unsigned)bf16_rne(e0) | ((unsigned)bf16_rne(e1) << 16);
            pk[t][1] = (unsigned)bf16_rne(e2) | ((unsigned)bf16_rne(e3) << 16);
            *(uint2*)(tileB + (size_t)(j0 >> 5) * 1024 + t * 512) = make_uint2(pk[t][0], pk[t][1]);
        }

        // ---- lane permutation: QK C-frag -> PV A-frag (8 shfl + select) ----
        union { unsigned u[4]; s16x8 v; } pa;
        {
            unsigned a0 = (unsigned)__shfl((int)pk[0][0], srcA);
            unsigned a1 = (unsigned)__shfl((int)pk[0][1], srcA);
            unsigned a2 = (unsigned)__shfl((int)pk[0][0], srcB);
            unsigned a3 = (unsigned)__shfl((int)pk[0][1], srcB);
            unsigned b0 = (unsigned)__shfl((int)pk[1][0], srcA);
            unsigned b1 = (unsigned)__shfl((int)pk[1][1], srcA);
            unsigned b2 = (unsigned)__shfl((int)pk[1][0], srcB);
            unsigned b3 = (unsigned)__shfl((int)pk[1][1], srcB);
            pa.u[0] = selT ? b0 : a0;
            pa.u[1] = selT ? b1 : a1;
            pa.u[2] = selT ? b2 : a2;
            pa.u[3] = selT ? b3 : a3;
        }

        // ---- PV ----
        __builtin_amdgcn_s_setprio(1);
#pragma unroll
        for (int nt2 = 0; nt2 < 4; ++nt2)
            pacc[nt2] = __builtin_amdgcn_mfma_f32_16x16x32_bf16(pa.v, vf[nt2], pacc[nt2], 0, 0, 0);
        __builtin_amdgcn_s_setprio(0);
        // prefetch V(next)
#pragma unroll
        for (int nt2 = 0; nt2 < 4; ++nt2)
            vf[nt2] = *(const s16x8*)(vB + (size_t)(nt2 * 16) * 4096 + jn);
    }

    zacc += __shfl_xor(zacc, 16);
    zacc += __shfl_xor(zacc, 32);
    if (ln < 16) atomicAdd(&z_g[(i0 + ln) * 4 + w], zacc);

#pragma unroll
    for (int nt2 = 0; nt2 < 4; ++nt2)
#pragma unroll
        for (int r = 0; r < 4; ++r)
            atomicAdd(&pacc_g[(size_t)(i0 + lhi * 4 + r) * 256 + w * 64 + nt2 * 16 + l15],
                      pacc[nt2][r]);
}

// ---------------------------------------------------------------------------
// ptilwh: fused ptil + A@Wh. Lane's p~ frags ARE the A-fragment; dsum/mask/
// exp in-register; ptil never leaves registers (redundant across the 4
// waves = 4 col-quarters). No LDS, no barriers. grid = 8 jch x 256 itl.
// ---------------------------------------------------------------------------
__global__ __launch_bounds__(256) void ptilwh_kernel(
    const unsigned short* __restrict__ pt_g, const unsigned short* __restrict__ wht_g,
    const int* __restrict__ adj, const float* __restrict__ p1g,
    const float* __restrict__ p2g, const float* __restrict__ p2m,
    const float* __restrict__ z_g,
    float* __restrict__ wacc_g, float* __restrict__ Lp_g)
{
    const int tid = threadIdx.x;
    const int w = tid >> 6;
    const int ln = tid & 63;
    const int l15 = ln & 15;
    const int lhi = ln >> 4;
    const int itl = blockIdx.x & 255;
    const int ch  = blockIdx.x >> 8;     // 0..7
    const int i = itl * 16 + l15;
    const int jb0 = ch * 16;             // 16 tiles of 32 j

    const float p1v = p1g[i];
    float Mfix;
    {
        float s = p1v + p2m[0];
        Mfix = (s > 0.f ? s : ALPHA_LR * s) + 4.0f;
    }
    float izv[4];
#pragma unroll
    for (int h = 0; h < 4; ++h) izv[h] = 1.0f / z_g[i * 4 + h];

    const char* ptB = (const char*)pt_g + (size_t)itl * 131072 + ln * 16;
    const int* adjB = adj + (size_t)i * 4096 + lhi * 8;
    const float* p2B = p2g + lhi * 8;
    const unsigned short* wB = wht_g + (size_t)(w * 64 + l15) * 4096 + lhi * 8;

    // prefetch tile 0
    u16x8 f0 = *(const u16x8*)(ptB + 0 * PT_HSTRIDE + (size_t)jb0 * 1024);
    u16x8 f1 = *(const u16x8*)(ptB + 1 * PT_HSTRIDE + (size_t)jb0 * 1024);
    u16x8 f2 = *(const u16x8*)(ptB + 2 * PT_HSTRIDE + (size_t)jb0 * 1024);
    u16x8 f3 = *(const u16x8*)(ptB + 3 * PT_HSTRIDE + (size_t)jb0 * 1024);
    int4 a0 = *(const int4*)(adjB + jb0 * 32);
    int4 a1 = *(const int4*)(adjB + jb0 * 32 + 4);
    float4 q0 = *(const float4*)(p2B + jb0 * 32);
    float4 q1 = *(const float4*)(p2B + jb0 * 32 + 4);
    s16x8 wf[4];
#pragma unroll
    for (int nt = 0; nt < 4; ++nt)
        wf[nt] = *(const s16x8*)(wB + (size_t)(nt * 16) * 4096 + jb0 * 32);

    f32x4 acc[4];
#pragma unroll
    for (int nt = 0; nt < 4; ++nt) acc[nt] = (f32x4){0.f, 0.f, 0.f, 0.f};
    float Lacc = 0.0f;

    for (int tt = 0; tt < 16; ++tt) {
        const int jbn = jb0 + ((tt + 1) & 15);

        // ---- ptil in-register (8 cells = the A-fragment) ----
        s16x8 pA;
        {
            int am[8] = {a0.x, a0.y, a0.z, a0.w, a1.x, a1.y, a1.z, a1.w};
            float pv[8] = {q0.x, q0.y, q0.z, q0.w, q1.x, q1.y, q1.z, q1.w};
#pragma unroll
            for (int e = 0; e < 8; ++e) {
                float ds = bf2f((unsigned short)f0[e]) * izv[0]
                         + bf2f((unsigned short)f1[e]) * izv[1]
                         + bf2f((unsigned short)f2[e]) * izv[2]
                         + bf2f((unsigned short)f3[e]) * izv[3];
                float ee = p1v + pv[e];
                ee = ee > 0.f ? ee : ALPHA_LR * ee;
                float pr = (am[e] > 0) ? __expf(ee + ds - Mfix) : 0.f;
                Lacc += pr;
                pA[e] = (short)bf16_rne(pr);
            }
        }
        // prefetch next tile's inputs
        f0 = *(const u16x8*)(ptB + 0 * PT_HSTRIDE + (size_t)jbn * 1024);
        f1 = *(const u16x8*)(ptB + 1 * PT_HSTRIDE + (size_t)jbn * 1024);
        f2 = *(const u16x8*)(ptB + 2 * PT_HSTRIDE + (size_t)jbn * 1024);
        f3 = *(const u16x8*)(ptB + 3 * PT_HSTRIDE + (size_t)jbn * 1024);
        a0 = *(const int4*)(adjB + jbn * 32);
        a1 = *(const int4*)(adjB + jbn * 32 + 4);
        q0 = *(const float4*)(p2B + jbn * 32);
        q1 = *(const float4*)(p2B + jbn * 32 + 4);

        // ---- A@Wh ----
        __builtin_amdgcn_s_setprio(1);
#pragma unroll
        for (int nt = 0; nt < 4; ++nt)
            acc[nt] = __builtin_amdgcn_mfma_f32_16x16x32_bf16(pA, wf[nt], acc[nt], 0, 0, 0);
        __builtin_amdgcn_s_setprio(0);
        // prefetch Wh frags
#pragma unroll
        for (int nt = 0; nt < 4; ++nt)
            wf[nt] = *(const s16x8*)(wB + (size_t)(nt * 16) * 4096 + jbn * 32);
    }

    Lacc += __shfl_xor(Lacc, 16);
    Lacc += __shfl_xor(Lacc, 32);
    if (w == 0 && ln < 16) atomicAdd(&Lp_g[itl * 16 + ln], Lacc);

#pragma unroll
    for (int nt = 0; nt < 4; ++nt)
#pragma unroll
        for (int r = 0; r < 4; ++r)
            atomicAdd(&wacc_g[(size_t)(itl * 16 + lhi * 4 + r) * 256 + w * 64 + nt * 16 + l15],
                      acc[nt][r]);
}

// ---------------------------------------------------------------------------
// Merge: Wh0 = pacc*iz -> row softmax; out = elu(wacc*invL + softmax(Wh0)).
// ---------------------------------------------------------------------------
__global__ __launch_bounds__(256) void merge_kernel(
    const float* __restrict__ pacc_g, const float* __restrict__ wacc_g,
    const float* __restrict__ z_g, const float* __restrict__ Lp,
    float* __restrict__ out)
{
    const int rt = blockIdx.x;
    const int tid = threadIdx.x;
    const int row = tid >> 4;
    const int cg = tid & 15;
    const int i = rt * 16 + row;

    const float iz = 1.0f / z_g[i * 4 + (cg >> 2)];
    const float invL = 1.0f / fmaxf(Lp[i], 1e-30f);

    float p[16], wv[16];
    const size_t b = (size_t)i * 256 + cg * 16;
#pragma unroll
    for (int k4 = 0; k4 < 4; ++k4) {
        float4 pvv = *(const float4*)(pacc_g + b + k4 * 4);
        float4 wvv = *(const float4*)(wacc_g + b + k4 * 4);
        p[k4*4+0] = pvv.x * iz; p[k4*4+1] = pvv.y * iz; p[k4*4+2] = pvv.z * iz; p[k4*4+3] = pvv.w * iz;
        wv[k4*4+0] = wvv.x; wv[k4*4+1] = wvv.y; wv[k4*4+2] = wvv.z; wv[k4*4+3] = wvv.w;
    }

    float mx = -3.0e38f;
#pragma unroll
    for (int k = 0; k < 16; ++k) mx = fmaxf(mx, p[k]);
    mx = wmax16(mx);
    float sm = 0.f;
#pragma unroll
    for (int k = 0; k < 16; ++k) { p[k] = __expf(p[k] - mx); sm += p[k]; }
    sm = wsum16(sm);
    const float inv = 1.0f / sm;

    float* orow = out + (size_t)i * 256 + cg * 16;
#pragma unroll
    for (int k4 = 0; k4 < 4; ++k4) {
        float4 o;
        float v;
        v = wv[k4*4+0] * invL + p[k4*4+0] * inv; o.x = v > 0.f ? v : __expf(v) - 1.f;
        v = wv[k4*4+1] * invL + p[k4*4+1] * inv; o.y = v > 0.f ? v : __expf(v) - 1.f;
        v = wv[k4*4+2] * invL + p[k4*4+2] * inv; o.z = v > 0.f ? v : __expf(v) - 1.f;
        v = wv[k4*4+3] * invL + p[k4*4+3] * inv; o.w = v > 0.f ? v : __expf(v) - 1.f;
        *(float4*)(orow + k4 * 4) = o;
    }
}

extern "C" void kernel_launch(void* const* d_in, const int* in_sizes, int n_in,
                              void* d_out, int out_size, void* d_ws, size_t ws_size,
                              hipStream_t stream)
{
    const float* h      = (const float*)d_in[0];
    const int*   adj    = (const int*)d_in[1];
    const float* W      = (const float*)d_in[2];
    const float* Wl_w   = (const float*)d_in[3];
    const float* Wl_b   = (const float*)d_in[4];
    const float* Wqkv_w = (const float*)d_in[5];
    const float* Wqkv_b = (const float*)d_in[6];
    const float* a      = (const float*)d_in[7];
    float* out = (float*)d_out;

    char* wsb = (char*)d_ws;
    unsigned short* qh     = (unsigned short*)(wsb + 0);           // 2 MB
    unsigned short* kh     = (unsigned short*)(wsb + 2097152);     // 2 MB
    unsigned short* vth    = (unsigned short*)(wsb + 4194304);     // 2 MB (vT [256][4096])
    unsigned short* wht    = (unsigned short*)(wsb + 6291456);     // 2 MB (WhT [256][4096])
    float*          pacc_f = (float*)(wsb + 8388608);              // 4 MB
    float*          wacc_f = (float*)(wsb + 12582912);             // 4 MB
    unsigned short* pt     = (unsigned short*)(wsb + 16777216);    // 128 MB p~ (full N, tiled)
    float*          p1b    = (float*)(wsb + 150994944);
    float*          p2b    = (float*)(wsb + 151011328);
    float*          p2m    = (float*)(wsb + 151027712);
    float*          qn2    = (float*)(wsb + 151031808);            // 64 KB
    float*          knp    = (float*)(wsb + 151097344);            // 16 KB
    float*          Mb     = (float*)(wsb + 151113728);            // 64 KB
    float*          z_g    = (float*)(wsb + 151179264);            // 64 KB
    float*          Lp     = (float*)(wsb + 151244800);            // 16 KB -> ends ~144.3 MB
    // gemm-phase temporaries overlay the p~ region (dead before qkexpv)
    unsigned short* Hhi    = (unsigned short*)(wsb + 16777216);    // 4 MB
    unsigned short* Hlo    = (unsigned short*)(wsb + 20971520);    // 4 MB
    unsigned short* WhbHi  = (unsigned short*)(wsb + 25165824);    // 2 MB
    unsigned short* WhbLo  = (unsigned short*)(wsb + 27262976);    // 2 MB
    unsigned short* Whi    = (unsigned short*)(wsb + 29360128);    // 256 KB
    unsigned short* Wlo    = (unsigned short*)(wsb + 29622272);
    unsigned short* Qhi    = (unsigned short*)(wsb + 29884416);    // 384 KB
    unsigned short* Qlo    = (unsigned short*)(wsb + 30277632);
    unsigned short* WLhi   = (unsigned short*)(wsb + 30670848);    // 128 KB
    unsigned short* WLlo   = (unsigned short*)(wsb + 30801920);
    unsigned short* WcThi  = (unsigned short*)(wsb + 30932992);    // 256 KB
    unsigned short* WcTlo  = (unsigned short*)(wsb + 31195136);

    hipMemsetAsync(pacc_f, 0, 4194304, stream);
    hipMemsetAsync(wacc_f, 0, 4194304, stream);
    hipMemsetAsync(z_g, 0, 65536, stream);
    hipMemsetAsync(Lp, 0, 16384, stream);

    dim3 blk(256);
    wprep<<<dim3(2048), blk, 0, stream>>>(W, Wqkv_w, Wl_w, h,
        Whi, Wlo, Qhi, Qlo, WLhi, WLlo, Hhi, Hlo);
    gemm_mfma<3, false><<<dim3(8, 4), blk, 0, stream>>>(
        WLhi, WLlo, Whi, Wlo, nullptr, WcThi, WcTlo, nullptr, 256, 512, 256);
    gemm_mfma<1, true><<<dim3(4, 64), blk, 0, stream>>>(
        Hhi, Hlo, WcThi, WcTlo, Wl_b, WhbHi, WhbLo, wht, 4096, 256, 512);
    gemm_mfma<2, true><<<dim3(12, 64), blk, 0, stream>>>(
        WhbHi, WhbLo, Qhi, Qlo, Wqkv_b, qh, kh, vth, 4096, 768, 256);
    compute_p<<<dim3(256), blk, 0, stream>>>(WhbHi, WhbLo, a, p1b, p2b);
    p2max_kernel<<<dim3(1), blk, 0, stream>>>(p2b, p2m);
    norms1<<<dim3(256), blk, 0, stream>>>(qh, kh, qn2, knp);
    norms2<<<dim3(16), blk, 0, stream>>>(qn2, knp, Mb);

    qkexpv_kernel<<<dim3(4096), blk, 0, stream>>>(qh, kh, vth, Mb, pt, z_g, pacc_f);
    ptilwh_kernel<<<dim3(2048), blk, 0, stream>>>(pt, wht, adj, p1b, p2b, p2m, z_g, wacc_f, Lp);
    merge_kernel<<<dim3(256), blk, 0, stream>>>(pacc_f, wacc_f, z_g, Lp, out);
}